// Round 8
// baseline (1147.731 us; speedup 1.0000x reference)
//
#include <hip/hip_runtime.h>

typedef unsigned short u16;
typedef unsigned int   u32;
typedef unsigned long long u64;
typedef __bf16 bf16x8 __attribute__((ext_vector_type(8)));
typedef float  f32x4  __attribute__((ext_vector_type(4)));
typedef float  f32x2  __attribute__((ext_vector_type(2)));
typedef int    i32x4  __attribute__((ext_vector_type(4)));
typedef u32    u32x2  __attribute__((ext_vector_type(2)));

#define Bn 8
#define Sn 96
#define Tn 96
#define Hn 64
#define H2n 128
#define NDIAG 191
#define STR 72            // state row stride (u16): 144B, 16B-aligned, 4-bank row stagger
#define ARR (Sn*STR)      // 6912 u16 per state array; 4 arrays = 55,296 B static LDS
#define WS_PX (Bn*2*Sn*Hn)  // fp32 px area in ws; flags (u32[Bn]) live right after

__device__ __forceinline__ float bf2f(u16 u){ return __uint_as_float(((u32)u)<<16); }
__device__ __forceinline__ u16 f2bf_rne(float f){
  u32 u = __float_as_uint(f);
  u += 0x7FFFu + ((u>>16)&1u);
  return (u16)(u>>16);
}
__device__ __forceinline__ u32 cvt_pk_bf16(float a, float b){
  u32 r;
  asm("v_cvt_pk_bf16_f32 %0, %1, %2" : "=v"(r) : "v"(a), "v"(b));
  return r;
}
__device__ __forceinline__ float lo16f(u32 u){ return __uint_as_float(u << 16); }
__device__ __forceinline__ float hi16f(u32 u){ return __uint_as_float(u & 0xFFFF0000u); }
__device__ __forceinline__ float fast_tanh(float x){
  float y = fminf(fmaxf(x+x, -30.f), 30.f);
  float e = __expf(y);
  return (e-1.f)*__builtin_amdgcn_rcpf(e+1.f);
}

// Prologue: depth-0 input projections + depth-0 bias into ws (fp32); zero sync flags.
__global__ __launch_bounds__(64) void proj0_kernel(
  const float* __restrict__ src, const float* __restrict__ trg,
  const float* __restrict__ Wix, const float* __restrict__ Wiy,
  const float* __restrict__ bx, const float* __restrict__ by,
  float* __restrict__ ws)
{
  const int row = blockIdx.x, g = blockIdx.y, b = blockIdx.z;
  const int n = threadIdx.x;
  if (blockIdx.x == 0 && blockIdx.y == 0 && threadIdx.x == 0)
    ((u32*)(ws + WS_PX))[b] = 0u;                    // flag[b] = 0 (overwrites 0xAA poison)
  const float* x = (g == 0) ? (src + (b*Sn + row)*Hn) : (trg + (b*Tn + row)*Hn);
  const float* W = (g == 0) ? Wix : Wiy;             // depth-0 slice
  float a = (g == 0) ? bx[n] : by[n];
  #pragma unroll 8
  for (int f = 0; f < Hn; ++f) a = fmaf(x[f], W[f*Hn + n], a);
  ws[((size_t)(b*2 + g)*Sn + row)*Hn + n] = a;
}

// Depth-split pipeline: grid (Bn, 2); block (b, dep) runs ALL 191 diagonals of its depth.
// dep1 consumes dep0's unmasked fp32 h from out (agent-scope stores), gated by flag[b].
// Per block: 16 waves = (g, nt, ms); ms interleaves mtiles {ms, ms+2, ms+4}.
// Round = { C: LDS state reads + MFMA + tanh (regs) ; bar ; W: state + out writes ; bar ; publish }.
__global__ __launch_bounds__(1024) void grid_rnn_dep(
  const float* __restrict__ Whx, const float* __restrict__ Why,
  const float* __restrict__ Wix, const float* __restrict__ Wiy,
  const float* __restrict__ bx,  const float* __restrict__ by,
  const int* __restrict__ src_lens, const int* __restrict__ trg_lens,
  float* __restrict__ out, float* __restrict__ ws)
{
  __shared__ __align__(16) u16 sXhi[ARR];   // column state hx(i-1,j) of own depth
  __shared__ __align__(16) u16 sXlo[ARR];
  __shared__ __align__(16) u16 sYhi[ARR];   // row state hy(i,j-1) of own depth
  __shared__ __align__(16) u16 sYlo[ARR];

  const int b   = blockIdx.x;
  const int dep = blockIdx.y;
  const int tid = threadIdx.x;
  const int lane= tid & 63;
  const int wid = tid >> 6;
  const int q   = lane >> 4;
  const int c   = lane & 15;
  const int g   = wid >> 3;
  const int nt  = (wid >> 1) & 3;
  const int ms  = wid & 1;
  const int sl = src_lens[b], tl = trg_lens[b];
  u32* flag = (u32*)(ws + WS_PX);

  for (int idx = tid; idx < ARR/2; idx += 1024){
    ((u32*)sXhi)[idx]=0u; ((u32*)sXlo)[idx]=0u;
    ((u32*)sYhi)[idx]=0u; ((u32*)sYlo)[idx]=0u;
  }

  // ---- recurrence weights (own depth, 16-feature tile), hi/lo bf16 split
  const float* Wh = (g ? Why : Whx) + dep*H2n*Hn;
  const int nb = nt*16 + c;
  i32x4 whf_h[4], whf_l[4];
  #pragma unroll
  for (int kk = 0; kk < 4; ++kk){
    #pragma unroll
    for (int p = 0; p < 4; ++p){
      float w0 = Wh[(kk*32 + q*8 + 2*p    )*Hn + nb];
      float w1 = Wh[(kk*32 + q*8 + 2*p + 1)*Hn + nb];
      u32 h0_ = f2bf_rne(w0), h1_ = f2bf_rne(w1);
      u32 l0_ = f2bf_rne(w0 - bf2f((u16)h0_));
      u32 l1_ = f2bf_rne(w1 - bf2f((u16)h1_));
      whf_h[kk][p] = (int)(h0_ | (h1_ << 16));
      whf_l[kk][p] = (int)(l0_ | (l1_ << 16));
    }
  }
  i32x4 wif_h[2], wif_l[2];
  f32x4 bias4 = {0.f, 0.f, 0.f, 0.f};
  if (dep == 1){
    const float* Wi = (g ? Wiy : Wix) + Hn*Hn;     // depth-1 slice
    #pragma unroll
    for (int kk = 0; kk < 2; ++kk){
      #pragma unroll
      for (int p = 0; p < 4; ++p){
        float w0 = Wi[(kk*32 + q*8 + 2*p    )*Hn + nb];
        float w1 = Wi[(kk*32 + q*8 + 2*p + 1)*Hn + nb];
        u32 h0_ = f2bf_rne(w0), h1_ = f2bf_rne(w1);
        u32 l0_ = f2bf_rne(w0 - bf2f((u16)h0_));
        u32 l1_ = f2bf_rne(w1 - bf2f((u16)h1_));
        wif_h[kk][p] = (int)(h0_ | (h1_ << 16));
        wif_l[kk][p] = (int)(l0_ | (l1_ << 16));
      }
    }
    const float* bb = (g ? by : bx) + Hn;          // depth-1 bias
    #pragma unroll
    for (int r4 = 0; r4 < 4; ++r4) bias4[r4] = bb[nt*16 + q*4 + r4];
  }
  const float* pxbase = ws + (size_t)(b*2 + g)*Sn*Hn;                       // dep0 acc init
  const float* h0base = out + (size_t)((g*2 + 0)*Bn + b)*(size_t)(Sn*Tn)*Hn; // dep1 operand
  float* outbase = out + (size_t)((g*2 + dep)*Bn + b)*(size_t)(Sn*Tn)*Hn;

  u32 lastSeen = 0;
  __syncthreads();

  for (int r = 0; r < NDIAG; ++r){
    if (dep == 1 && lastSeen < (u32)(r+1)){
      u32 f;
      do { f = __hip_atomic_load(flag + b, __ATOMIC_ACQUIRE, __HIP_MEMORY_SCOPE_AGENT); }
      while (f < (u32)(r+1));
      lastSeen = f;
    }
    const int i0 = (r > Tn-1) ? r - (Tn-1) : 0;
    const int i1 = (r < Sn-1) ? r : Sn-1;
    const int nc = i1 - i0 + 1;
    const int mtiles = (nc + 15) >> 4;

    u32x2 hvp[3], lvp[3];
    int iv[3]; bool val[3];

    // ---- C phase: read state + compute; no state writes
    #pragma unroll
    for (int uu = 0; uu < 3; ++uu){
      const int mt = ms + 2*uu;
      const bool act = (mt < mtiles);
      const int cell = mt*16 + c;
      val[uu] = act && (cell < nc);
      const int cc = (cell < nc) ? cell : nc - 1;
      const int i = i0 + cc, j = r - i;
      iv[uu] = i;
      if (!act) continue;

      f32x4 acc;
      f32x4 f0a, f0b, f1a, f1b;
      if (dep == 0){
        acc = *(const f32x4*)(pxbase + (size_t)((g == 0) ? i : j)*Hn + nt*16 + q*4);
      } else {
        acc = bias4;
        const float* h0row = h0base + (size_t)(i*Tn + j)*Hn;   // issued early, used late
        f0a = *(const f32x4*)(h0row + q*8);
        f0b = *(const f32x4*)(h0row + q*8 + 4);
        f1a = *(const f32x4*)(h0row + 32 + q*8);
        f1b = *(const f32x4*)(h0row + 32 + q*8 + 4);
      }
      // recurrence: K=128 (kk0-1: hx from col j; kk2-3: hy from row i), 3-product hi/lo
      #pragma unroll
      for (int kk = 0; kk < 4; ++kk){
        const int off = (kk < 2) ? (j*STR + kk*32 + q*8) : (i*STR + (kk-2)*32 + q*8);
        const u16* hb_ = (kk < 2) ? sXhi : sYhi;
        const u16* lb_ = (kk < 2) ? sXlo : sYlo;
        i32x4 shi = *(const i32x4*)(hb_ + off);
        i32x4 slo = *(const i32x4*)(lb_ + off);
        acc = __builtin_amdgcn_mfma_f32_16x16x32_bf16(
                __builtin_bit_cast(bf16x8, whf_h[kk]),
                __builtin_bit_cast(bf16x8, shi), acc, 0, 0, 0);
        acc = __builtin_amdgcn_mfma_f32_16x16x32_bf16(
                __builtin_bit_cast(bf16x8, whf_h[kk]),
                __builtin_bit_cast(bf16x8, slo), acc, 0, 0, 0);
        acc = __builtin_amdgcn_mfma_f32_16x16x32_bf16(
                __builtin_bit_cast(bf16x8, whf_l[kk]),
                __builtin_bit_cast(bf16x8, shi), acc, 0, 0, 0);
      }
      // dep1 projection from dep0's fp32 h row: hi/lo split on read
      if (dep == 1){
        i32x4 ph_[2], pl_[2];
        #pragma unroll
        for (int kk = 0; kk < 2; ++kk){
          f32x4 fa = kk ? f1a : f0a;
          f32x4 fb = kk ? f1b : f0b;
          u32 p0 = cvt_pk_bf16(fa[0], fa[1]);
          u32 p1 = cvt_pk_bf16(fa[2], fa[3]);
          u32 p2 = cvt_pk_bf16(fb[0], fb[1]);
          u32 p3 = cvt_pk_bf16(fb[2], fb[3]);
          ph_[kk][0]=(int)p0; ph_[kk][1]=(int)p1; ph_[kk][2]=(int)p2; ph_[kk][3]=(int)p3;
          pl_[kk][0] = (int)cvt_pk_bf16(fa[0]-lo16f(p0), fa[1]-hi16f(p0));
          pl_[kk][1] = (int)cvt_pk_bf16(fa[2]-lo16f(p1), fa[3]-hi16f(p1));
          pl_[kk][2] = (int)cvt_pk_bf16(fb[0]-lo16f(p2), fb[1]-hi16f(p2));
          pl_[kk][3] = (int)cvt_pk_bf16(fb[2]-lo16f(p3), fb[3]-hi16f(p3));
        }
        #pragma unroll
        for (int kk = 0; kk < 2; ++kk){
          acc = __builtin_amdgcn_mfma_f32_16x16x32_bf16(
                  __builtin_bit_cast(bf16x8, wif_h[kk]),
                  __builtin_bit_cast(bf16x8, ph_[kk]), acc, 0, 0, 0);
          acc = __builtin_amdgcn_mfma_f32_16x16x32_bf16(
                  __builtin_bit_cast(bf16x8, wif_h[kk]),
                  __builtin_bit_cast(bf16x8, pl_[kk]), acc, 0, 0, 0);
          acc = __builtin_amdgcn_mfma_f32_16x16x32_bf16(
                  __builtin_bit_cast(bf16x8, wif_l[kk]),
                  __builtin_bit_cast(bf16x8, ph_[kk]), acc, 0, 0, 0);   // bug fixed: ph, not pl
        }
      }
      // tanh -> packed hi/lo carried across the barrier
      float h0v = fast_tanh(acc[0]), h1v = fast_tanh(acc[1]);
      float h2v = fast_tanh(acc[2]), h3v = fast_tanh(acc[3]);
      u32 a01 = cvt_pk_bf16(h0v, h1v), a23 = cvt_pk_bf16(h2v, h3v);
      hvp[uu][0] = a01; hvp[uu][1] = a23;
      lvp[uu][0] = cvt_pk_bf16(h0v - lo16f(a01), h1v - hi16f(a01));
      lvp[uu][1] = cvt_pk_bf16(h2v - lo16f(a23), h3v - hi16f(a23));
    }
    __syncthreads();

    // ---- W phase: state writes + out writes
    #pragma unroll
    for (int uu = 0; uu < 3; ++uu){
      if (!val[uu]) continue;
      const int i = iv[uu], j = r - i;
      const int n0 = nt*16 + q*4;
      u16* st_hi = ((g == 0) ? (sXhi + j*STR) : (sYhi + i*STR)) + n0;
      u16* st_lo = ((g == 0) ? (sXlo + j*STR) : (sYlo + i*STR)) + n0;
      *(u32x2*)st_hi = hvp[uu];
      *(u32x2*)st_lo = lvp[uu];
      f32x4 ov;
      ov[0] = lo16f(hvp[uu][0]) + lo16f(lvp[uu][0]);
      ov[1] = hi16f(hvp[uu][0]) + hi16f(lvp[uu][0]);
      ov[2] = lo16f(hvp[uu][1]) + lo16f(lvp[uu][1]);
      ov[3] = hi16f(hvp[uu][1]) + hi16f(lvp[uu][1]);
      float* outg = outbase + (size_t)(i*Tn + j)*Hn + n0;
      if (dep == 0){
        // UNMASKED, agent-visible (dep1 on another CU/XCD reads these)
        f32x2 v01 = {ov[0], ov[1]}, v23 = {ov[2], ov[3]};
        __hip_atomic_store((u64*)outg,     __builtin_bit_cast(u64, v01),
                           __ATOMIC_RELAXED, __HIP_MEMORY_SCOPE_AGENT);
        __hip_atomic_store(((u64*)outg)+1, __builtin_bit_cast(u64, v23),
                           __ATOMIC_RELAXED, __HIP_MEMORY_SCOPE_AGENT);
      } else {
        if (i >= sl || j >= tl) ov = (f32x4)(0.f);     // depth-1 masked at store
        *(f32x4*)outg = ov;
      }
    }
    __syncthreads();
    if (dep == 0 && tid == 0)
      __hip_atomic_store(flag + b, (u32)(r+1), __ATOMIC_RELEASE, __HIP_MEMORY_SCOPE_AGENT);
  }

  // dep1 is the unique last consumer of dep0's unmasked outputs -> it applies the mask
  if (dep == 1){
    for (int idx = tid; idx < Sn*Tn; idx += 1024){
      const int i = idx / Tn, j = idx - (idx/Tn)*Tn;
      if (i >= sl || j >= tl){
        float* p0 = out + ((size_t)(0*Bn + b)*(Sn*Tn) + idx)*Hn;   // plane 0: hx depth-0
        float* p2 = out + ((size_t)(2*Bn + b)*(Sn*Tn) + idx)*Hn;   // plane 2: hy depth-0
        f32x4 z = (f32x4)(0.f);
        #pragma unroll
        for (int t8 = 0; t8 < 16; ++t8){ ((f32x4*)p0)[t8] = z; ((f32x4*)p2)[t8] = z; }
      }
    }
  }
}

extern "C" void kernel_launch(void* const* d_in, const int* in_sizes, int n_in,
                              void* d_out, int out_size, void* d_ws, size_t ws_size,
                              hipStream_t stream) {
  (void)in_sizes; (void)n_in; (void)out_size; (void)ws_size;
  proj0_kernel<<<dim3(Sn, 2, Bn), 64, 0, stream>>>(
      (const float*)d_in[0], (const float*)d_in[1],
      (const float*)d_in[2], (const float*)d_in[5],
      (const float*)d_in[4], (const float*)d_in[7],
      (float*)d_ws);
  grid_rnn_dep<<<dim3(Bn, 2), dim3(1024), 0, stream>>>(
      (const float*)d_in[3], (const float*)d_in[6],
      (const float*)d_in[2], (const float*)d_in[5],
      (const float*)d_in[4], (const float*)d_in[7],
      (const int*)d_in[8], (const int*)d_in[9],
      (float*)d_out, (float*)d_ws);
}